// Round 1
// baseline (205.999 us; speedup 1.0000x reference)
//
#include <hip/hip_runtime.h>

#define B_ 16
#define C_ 256
#define N_ 16384      // 128*128
#define NT_ 16        // n-tiles for kernel 1
#define NTILE_ 1024   // N_/NT_ (256 threads * float4)
#define R_ 16         // reduced dim

// ---------------------------------------------------------------------------
// K1: colsum[b,n] = sum_c x[b,c,n]; Tpart[b,tile] = partial batch total.
// Grid (B_, NT_) x 256 threads. Each block owns 1024 consecutive n, loops c.
// Coalesced float4 loads; colsum kept in registers -> single write, no atomics.
// ---------------------------------------------------------------------------
__global__ void k1_colsum(const float* __restrict__ x,
                          float* __restrict__ colsum,
                          float* __restrict__ Tpart) {
    const int b = blockIdx.x;
    const int tile = blockIdx.y;
    const int tid = threadIdx.x;
    const int n0 = tile * NTILE_ + tid * 4;
    const float* xb = x + (size_t)b * C_ * N_ + n0;

    float4 acc = make_float4(0.f, 0.f, 0.f, 0.f);
#pragma unroll 8
    for (int c = 0; c < C_; ++c) {
        float4 vx = *reinterpret_cast<const float4*>(xb + (size_t)c * N_);
        acc.x += vx.x; acc.y += vx.y; acc.z += vx.z; acc.w += vx.w;
    }
    *reinterpret_cast<float4*>(colsum + b * N_ + n0) = acc;

    // block-reduce for the batch-total partial
    float s = acc.x + acc.y + acc.z + acc.w;
#pragma unroll
    for (int off = 32; off; off >>= 1) s += __shfl_down(s, off, 64);
    __shared__ float red[4];
    if ((tid & 63) == 0) red[tid >> 6] = s;
    __syncthreads();
    if (tid == 0) Tpart[b * NT_ + tile] = red[0] + red[1] + red[2] + red[3];
}

// ---------------------------------------------------------------------------
// K2: v[b,c] = sum_n x[b,c,n] * (colsum[b,n] - T[b]/N) / ((N-1)*C)
// Grid (C_, B_) x 256 threads; one block per (b,c) row. colsum row (64 KiB)
// is shared by all 256 c-blocks of a batch -> L2 hits.
// ---------------------------------------------------------------------------
__global__ void k2_v(const float* __restrict__ x,
                     const float* __restrict__ colsum,
                     const float* __restrict__ Tpart,
                     float* __restrict__ v) {
    const int c = blockIdx.x;
    const int b = blockIdx.y;
    const int tid = threadIdx.x;

    float Tb = 0.f;
#pragma unroll
    for (int t = 0; t < NT_; ++t) Tb += Tpart[b * NT_ + t];
    const float mean_s = Tb / (float)N_;

    const float* xr = x + ((size_t)b * C_ + c) * N_;
    const float* cs = colsum + b * N_;

    float acc = 0.f;
#pragma unroll 4
    for (int n = tid * 4; n < N_; n += 256 * 4) {
        float4 vx = *reinterpret_cast<const float4*>(xr + n);
        float4 vs = *reinterpret_cast<const float4*>(cs + n);
        acc += vx.x * (vs.x - mean_s) + vx.y * (vs.y - mean_s)
             + vx.z * (vs.z - mean_s) + vx.w * (vs.w - mean_s);
    }
#pragma unroll
    for (int off = 32; off; off >>= 1) acc += __shfl_down(acc, off, 64);
    __shared__ float red[4];
    if ((tid & 63) == 0) red[tid >> 6] = acc;
    __syncthreads();
    if (tid == 0) {
        const float denom = (float)(N_ - 1) * (float)C_;
        v[b * C_ + c] = (red[0] + red[1] + red[2] + red[3]) / denom;
    }
}

// ---------------------------------------------------------------------------
// K3: tiny MLP  v[16,256] -> relu(v@w1^T+b1)[16,16] -> sigmoid(@w2^T+b2)[16,256]
// Single block, 256 threads.
// ---------------------------------------------------------------------------
__global__ void k3_mlp(const float* __restrict__ v,
                       const float* __restrict__ w1,
                       const float* __restrict__ b1,
                       const float* __restrict__ w2,
                       const float* __restrict__ b2,
                       float* __restrict__ gate) {
    __shared__ float vl[B_ * C_];
    __shared__ float h1[B_ * R_];
    const int tid = threadIdx.x;

    for (int i = tid; i < B_ * C_; i += 256) vl[i] = v[i];
    __syncthreads();

    {   // 256 threads == 16*16 h1 entries
        const int b = tid >> 4, i = tid & 15;
        float a = b1[i];
#pragma unroll 8
        for (int c = 0; c < C_; ++c) a += vl[b * C_ + c] * w1[i * C_ + c];
        h1[b * R_ + i] = a > 0.f ? a : 0.f;
    }
    __syncthreads();

    {   // thread tid owns channel c = tid for all 16 batches
        const int c = tid;
        const float bias = b2[c];
        for (int b = 0; b < B_; ++b) {
            float a = bias;
#pragma unroll
            for (int i = 0; i < R_; ++i) a += h1[b * R_ + i] * w2[c * R_ + i];
            gate[b * C_ + c] = 1.f / (1.f + __expf(-a));
        }
    }
}

// ---------------------------------------------------------------------------
// K4: out = x * gate[b,c], grid-stride float4.
// ---------------------------------------------------------------------------
__global__ void k4_scale(const float* __restrict__ x,
                         const float* __restrict__ gate,
                         float* __restrict__ out) {
    const size_t total4 = (size_t)B_ * C_ * N_ / 4;
    for (size_t i = (size_t)blockIdx.x * blockDim.x + threadIdx.x; i < total4;
         i += (size_t)gridDim.x * blockDim.x) {
        const int bc = (int)(i >> 12);           // N_/4 = 4096 float4 per (b,c)
        const float g = gate[bc];
        float4 vx = reinterpret_cast<const float4*>(x)[i];
        float4 r = make_float4(vx.x * g, vx.y * g, vx.z * g, vx.w * g);
        reinterpret_cast<float4*>(out)[i] = r;
    }
}

extern "C" void kernel_launch(void* const* d_in, const int* in_sizes, int n_in,
                              void* d_out, int out_size, void* d_ws, size_t ws_size,
                              hipStream_t stream) {
    (void)in_sizes; (void)n_in; (void)out_size; (void)ws_size;
    const float* x  = (const float*)d_in[0];
    const float* w1 = (const float*)d_in[1];
    const float* b1 = (const float*)d_in[2];
    const float* w2 = (const float*)d_in[3];
    const float* b2 = (const float*)d_in[4];
    float* out = (float*)d_out;

    float* ws     = (float*)d_ws;
    float* colsum = ws;                          // B_*N_   = 262144 floats
    float* Tpart  = colsum + (size_t)B_ * N_;    // B_*NT_  = 256
    float* v      = Tpart + B_ * NT_;            // B_*C_   = 4096
    float* gate   = v + B_ * C_;                 // B_*C_   = 4096

    hipLaunchKernelGGL(k1_colsum, dim3(B_, NT_), dim3(256), 0, stream,
                       x, colsum, Tpart);
    hipLaunchKernelGGL(k2_v, dim3(C_, B_), dim3(256), 0, stream,
                       x, colsum, Tpart, v);
    hipLaunchKernelGGL(k3_mlp, dim3(1), dim3(256), 0, stream,
                       v, w1, b1, w2, b2, gate);
    hipLaunchKernelGGL(k4_scale, dim3(2048), dim3(256), 0, stream,
                       x, gate, out);
}